// Round 12
// baseline (271.588 us; speedup 1.0000x reference)
//
#include <hip/hip_runtime.h>
#include <hip/hip_bf16.h>

#define BB 8
#define NN 2048
#define MM 2048
#define DD 512

typedef __attribute__((ext_vector_type(8))) _Float16 f16x8;
typedef __attribute__((ext_vector_type(4))) float f32x4;
typedef __attribute__((ext_vector_type(8))) unsigned short u16x8;

__device__ __forceinline__ unsigned short f2h(float x){
  union { _Float16 h; unsigned short u; } cv;
  cv.h = (_Float16)x;           // v_cvt_f16_f32, RTN-even
  return cv.u;
}
__device__ __forceinline__ f32x4 mfmah(f16x8 a, f16x8 b, f32x4 c){
  return __builtin_amdgcn_mfma_f32_16x16x32_f16(a, b, c, 0, 0, 0);
}

// async global->LDS, 16B per lane; LDS dest is wave-uniform base + lane*16
#define GLD16(gp, lp) __builtin_amdgcn_global_load_lds( \
    (const __attribute__((address_space(1))) void*)(gp), \
    (__attribute__((address_space(3))) void*)(lp), 16, 0, 0)

// wait until <= n vector-memory ops outstanding
#define WAITVM(n) __builtin_amdgcn_s_waitcnt(0xF70 | (n))

// batch->XCD swizzle: flat id f -> bz = f&7 (XCD presumed f%8), bijective
// (requires gridDim.z == 8)
__device__ __forceinline__ void swz_xyz(int& bn, int& bm, int& bz){
  int f = ((int)blockIdx.z * (int)gridDim.y + (int)blockIdx.y) * (int)gridDim.x
        + (int)blockIdx.x;
  bz = f & 7;
  int r = f >> 3;
  bn = r % (int)gridDim.x;
  bm = r / (int)gridDim.x;
}

// ---------------------------------------------------------------------------
// cvt16: f32 -> f16, float4-vectorized, grid-stride
// ---------------------------------------------------------------------------
__global__ __launch_bounds__(256) void cvt16_kernel(const float* __restrict__ in,
    unsigned short* __restrict__ out, int n4){
  int i = blockIdx.x*256 + threadIdx.x;
  const int stride = gridDim.x*256;
  for (; i < n4; i += stride){
    float4 v = ((const float4*)in)[i];
    ushort4 h; h.x=f2h(v.x); h.y=f2h(v.y); h.z=f2h(v.z); h.w=f2h(v.w);
    ((ushort4*)out)[i] = h;
  }
}

// ---------------------------------------------------------------------------
// cam_prep: one pass over camera f32 -> camH f16 AND svec[row] = cam.c2
// ---------------------------------------------------------------------------
__global__ __launch_bounds__(256) void cam_prep(const float* __restrict__ cam,
    const float* __restrict__ c2,
    unsigned short* __restrict__ camH,
    float* __restrict__ svec){
  const int t = threadIdx.x;
  const int l = t & 63;
  const size_t row = (size_t)blockIdx.x*4 + (t >> 6);
  const float4* r4 = (const float4*)(cam + row*DD);
  const float4* c4 = (const float4*)c2;
  float4 v0 = r4[l*2],   v1 = r4[l*2+1];
  float4 a0 = c4[l*2],   a1 = c4[l*2+1];
  float p = v0.x*a0.x + v0.y*a0.y + v0.z*a0.z + v0.w*a0.w
          + v1.x*a1.x + v1.y*a1.y + v1.z*a1.z + v1.w*a1.w;
  for (int o = 32; o; o >>= 1) p += __shfl_xor(p, o);
  if (l == 0) svec[row] = p;
  ushort4 h0; h0.x=f2h(v0.x); h0.y=f2h(v0.y); h0.z=f2h(v0.z); h0.w=f2h(v0.w);
  ushort4 h1; h1.x=f2h(v1.x); h1.y=f2h(v1.y); h1.z=f2h(v1.z); h1.w=f2h(v1.w);
  ushort4* dst = (ushort4*)(camH + row*DD);
  dst[l*2]   = h0;
  dst[l*2+1] = h1;
}

// ---------------------------------------------------------------------------
// K0: At[j][i] = sum_e Wq[e][i] * Wk[e][j], f32 accum, f16 out
// ---------------------------------------------------------------------------
__global__ __launch_bounds__(256) void at_kernel(const float* __restrict__ Wq,
                                                 const float* __restrict__ Wk,
                                                 unsigned short* __restrict__ atH){
  const int i0 = blockIdx.x * 32, j0 = blockIdx.y * 32;
  __shared__ float q_s[32][33];
  __shared__ float k_s[32][33];
  const int t = threadIdx.x;
  const int tx = t & 15, ty = t >> 4;
  float acc[2][2] = {{0.f,0.f},{0.f,0.f}};
  for (int e0 = 0; e0 < DD; e0 += 32){
    __syncthreads();
#pragma unroll
    for (int p = 0; p < 4; ++p){
      int idx = t + 256*p;
      int e = idx >> 5, c = idx & 31;
      q_s[e][c] = Wq[(size_t)(e0+e)*DD + i0 + c];
      k_s[e][c] = Wk[(size_t)(e0+e)*DD + j0 + c];
    }
    __syncthreads();
#pragma unroll 8
    for (int e = 0; e < 32; ++e){
      float q0 = q_s[e][2*tx], q1 = q_s[e][2*tx+1];
      float k0 = k_s[e][2*ty], k1 = k_s[e][2*ty+1];
      acc[0][0] += k0*q0; acc[0][1] += k0*q1;
      acc[1][0] += k1*q0; acc[1][1] += k1*q1;
    }
  }
#pragma unroll
  for (int a = 0; a < 2; ++a)
#pragma unroll
    for (int b = 0; b < 2; ++b)
      atH[(size_t)(j0 + 2*ty + a)*DD + i0 + 2*tx + b] = f2h(acc[a][b]);
}

// c2[d] = sum_e bq[e] * Wk[e][d]
__global__ __launch_bounds__(256) void c2_kernel(const float* __restrict__ bq,
                                                 const float* __restrict__ Wk,
                                                 float* __restrict__ c2){
  int d = blockIdx.x * 256 + threadIdx.x;
  float a = 0.f;
  for (int e = 0; e < DD; ++e) a += bq[e] * Wk[(size_t)e*DD + d];
  c2[d] = a;
}

// ---------------------------------------------------------------------------
// Plain f16 GEMM, BT form: O[row,col] = sum_k A[row,k]*B[col,k], f16 out.
// Block 128x128, 4 waves 2x2, wave 64x64 (4x4 frags of 16x16x32 f16).
// MODE 0: plain.  MODE 1: + bias[row].
// ---------------------------------------------------------------------------
template<int MODE>
__global__ __launch_bounds__(256) void gemm_h128(
    const unsigned short* __restrict__ Ag, long sA, int lda,
    const unsigned short* __restrict__ Bg, long sB, int ldb,
    unsigned short* __restrict__ O, long sO, int ldo,
    const float* __restrict__ bias)
{
  __shared__ __attribute__((aligned(16))) unsigned short Ah[128][40];
  __shared__ __attribute__((aligned(16))) unsigned short Bh[128][40];

  int bn, bm, bz; swz_xyz(bn, bm, bz);
  const int t = threadIdx.x;
  const int lane = t & 63, w = t >> 6;
  const int wrow = w >> 1, wcol = w & 1;
  const int lr = lane & 15, lk = (lane >> 4) << 3;

  f32x4 acc[4][4];
#pragma unroll
  for (int m = 0; m < 4; ++m)
#pragma unroll
    for (int n = 0; n < 4; ++n){ f32x4 z = {0.f,0.f,0.f,0.f}; acc[m][n] = z; }

  const unsigned short* Ap = Ag + (size_t)bz*(size_t)sA + ((size_t)bm*128)*(size_t)lda;
  const unsigned short* Bp = Bg + (size_t)bz*(size_t)sB + ((size_t)bn*128)*(size_t)ldb;

  const int sr = t >> 2;          // 0..63
  const int sc = (t & 3) * 8;

  for (int k0 = 0; k0 < DD; k0 += 32){
    __syncthreads();
#pragma unroll
    for (int p = 0; p < 2; ++p){
      int r = sr + 64*p;
      *(u16x8*)&Ah[r][sc] = *(const u16x8*)(Ap + (size_t)r*lda + k0 + sc);
      *(u16x8*)&Bh[r][sc] = *(const u16x8*)(Bp + (size_t)r*ldb + k0 + sc);
    }
    __syncthreads();

    f16x8 af[4], bf[4];
#pragma unroll
    for (int m = 0; m < 4; ++m) af[m] = *(const f16x8*)&Ah[wrow*64 + m*16 + lr][lk];
#pragma unroll
    for (int n = 0; n < 4; ++n) bf[n] = *(const f16x8*)&Bh[wcol*64 + n*16 + lr][lk];
#pragma unroll
    for (int m = 0; m < 4; ++m)
#pragma unroll
      for (int n = 0; n < 4; ++n)
        acc[m][n] = mfmah(af[m], bf[n], acc[m][n]);
  }

  const int orow = bm*128 + wrow*64;
  const int ocol = bn*128 + wcol*64;
#pragma unroll
  for (int m = 0; m < 4; ++m){
#pragma unroll
    for (int n = 0; n < 4; ++n){
      int col  = ocol + n*16 + lr;
      int row0 = orow + m*16 + ((lane >> 4) << 2);
#pragma unroll
      for (int r = 0; r < 4; ++r){
        int row = row0 + r;
        float v = acc[m][n][r];
        if constexpr (MODE == 1) v += bias[row];
        O[(size_t)bz*(size_t)sO + (size_t)row*ldo + col] = f2h(v);
      }
    }
  }
}

// ---------------------------------------------------------------------------
// FLASH: fused scores+softmax+PV.
//   out[n,:] = softmax_m( conf[n]*(T[n,:].cam[m,:] + svec[m]) ) @ V
// Block = 64 Q-rows, 8 waves (512 thr); grid 256 = (32 nb x 8 batch),
// batch-per-XCD swizzle (bz = f&7) so cam+Vt (4MB/batch) ~fit XCD L2.
// R11 crash root-cause: grid was (64,8) -> nb up to 63 -> OOB rows
// (bz*2048 + nb*64 up to 18431 >= 16384).  N/64 = 32 blocks per batch.
// LDS: T tile [64][520] resident; cam m-tiles (32 rows) double-buffered via
// global_load_lds; P bounce [64][40]; softmax state arrays (~140 KB total,
// 1 block/CU).
// S phase: wave w -> frag (r=w>>1 rows, c=w&1 cols), K=512 (16 MFMA).
// PV phase: wave w -> e-slice w*64 (4x4 frags, 16 MFMA), Vt B-frags direct
// from global (L2).  Online softmax: 16-lane shfl row-max/sum + cross-c-wave
// LDS reduce; acc rescaled by exp(m_old-m_new); epilogue divides by l.
// 3 barriers/iter; WAR separations verified barrier-by-barrier.
// ---------------------------------------------------------------------------
__global__ __launch_bounds__(512) void flash_kernel(
    const unsigned short* __restrict__ Th,    // [B,N,D] f16
    const unsigned short* __restrict__ camH,  // [B,M,D] f16
    const unsigned short* __restrict__ Vt,    // [B,D,M] f16
    const float* __restrict__ conf,           // [B,N,1]
    const float* __restrict__ svec,           // [B,M]
    float* __restrict__ O)                    // [B,N,D] f32
{
  __shared__ unsigned short T_s[64][520];       // 66.5 KB, resident
  __shared__ unsigned short cam_s[2][32][520];  // 66.5 KB, dbuf
  __shared__ unsigned short P_s[64][40];        // 5 KB
  __shared__ float redm[2][64], reds[2][64], resc_s[64];
  __shared__ float mrun[64], lrun[64], conf_s[64];

  const int f  = (int)blockIdx.y * 32 + (int)blockIdx.x;  // grid (32,8)
  const int bz = f & 7;          // batch -> XCD
  const int nb = f >> 3;         // 0..31: n-block within batch
  const int t = threadIdx.x, lane = t & 63, w = t >> 6;
  const int r = w >> 1, c = w & 1;          // S-frag assignment
  const int g = lane >> 4, l15 = lane & 15;

  const unsigned short* Tg   = Th   + ((size_t)bz*NN + (size_t)nb*64)*DD;
  const unsigned short* camg = camH + (size_t)bz*((size_t)MM*DD);
  const unsigned short* Vtg  = Vt   + (size_t)bz*((size_t)DD*MM);

  // prologue: T tile -> LDS (once)
#pragma unroll
  for (int j = 0; j < 8; ++j){
    int idx = j*512 + t;
    int row = idx >> 6, ch = idx & 63;
    *(u16x8*)&T_s[row][ch*8] = *(const u16x8*)(Tg + (size_t)row*DD + ch*8);
  }
  if (t < 64){
    mrun[t] = -3.0e38f; lrun[t] = 0.f;
    conf_s[t] = conf[bz*NN + nb*64 + t];
  }

  // wave w stages rows 4w..4w+3 of a cam tile; one gload16 = one full row
#define STAGECAM(bufi, m0_) do {                                            \
    _Pragma("unroll")                                                       \
    for (int j = 0; j < 4; ++j)                                             \
      GLD16(camg + (size_t)((m0_) + 4*w + j)*DD + lane*8,                   \
            &cam_s[bufi][4*w + j][0]);                                      \
  } while(0)

  STAGECAM(0, 0);
  WAITVM(0);
  __syncthreads();

  f32x4 acc[4][4];    // out[64 n][wave's 64 e]: nf x ef
#pragma unroll
  for (int nf = 0; nf < 4; ++nf)
#pragma unroll
    for (int ef = 0; ef < 4; ++ef){ f32x4 z = {0.f,0.f,0.f,0.f}; acc[nf][ef] = z; }

  for (int mt = 0; mt < 64; ++mt){
    const int m0 = mt*32;
    const int buf = mt & 1;
    if (mt < 63) STAGECAM(buf^1, m0+32);     // target buf last read at mt-1;
                                             // all waves passed B3(mt-1)
    // prefetch Vt B-frags (flight hidden under S+softmax; waited at WAITVM)
    f16x8 bf[4];
#pragma unroll
    for (int ef = 0; ef < 4; ++ef)
      bf[ef] = *(const f16x8*)(Vtg + (size_t)(w*64 + ef*16 + l15)*MM + m0 + g*8);
    const float sv = svec[bz*MM + m0 + c*16 + l15];

    // S = T.cam^T for this wave's 16x16 frag, K=512
    f32x4 sacc = {0.f,0.f,0.f,0.f};
#pragma unroll
    for (int kk = 0; kk < 16; ++kk){
      f16x8 a = *(const f16x8*)&T_s[r*16 + l15][kk*32 + g*8];
      f16x8 b = *(const f16x8*)&cam_s[buf][c*16 + l15][kk*32 + g*8];
      sacc = mfmah(a, b, sacc);
    }

    // logits + per-row max (rows R(q) = r*16 + g*4 + q; cols = 16 lanes)
    float s0 = conf_s[r*16 + g*4 + 0] * (sacc[0] + sv);
    float s1 = conf_s[r*16 + g*4 + 1] * (sacc[1] + sv);
    float s2 = conf_s[r*16 + g*4 + 2] * (sacc[2] + sv);
    float s3 = conf_s[r*16 + g*4 + 3] * (sacc[3] + sv);
    float m0_ = s0, m1_ = s1, m2_ = s2, m3_ = s3;
#pragma unroll
    for (int msk = 1; msk <= 8; msk <<= 1){
      m0_ = fmaxf(m0_, __shfl_xor(m0_, msk));
      m1_ = fmaxf(m1_, __shfl_xor(m1_, msk));
      m2_ = fmaxf(m2_, __shfl_xor(m2_, msk));
      m3_ = fmaxf(m3_, __shfl_xor(m3_, msk));
    }
    if (l15 == 0){
      redm[c][r*16 + g*4 + 0] = m0_;
      redm[c][r*16 + g*4 + 1] = m1_;
      redm[c][r*16 + g*4 + 2] = m2_;
      redm[c][r*16 + g*4 + 3] = m3_;
    }
    __syncthreads();                                   // B1
    if (t < 64){
      float nm = fmaxf(mrun[t], fmaxf(redm[0][t], redm[1][t]));
      resc_s[t] = __expf(mrun[t] - nm);
      mrun[t] = nm;
    }
    __syncthreads();                                   // B2
    float p0 = __expf(s0 - mrun[r*16 + g*4 + 0]);
    float p1 = __expf(s1 - mrun[r*16 + g*4 + 1]);
    float p2 = __expf(s2 - mrun[r*16 + g*4 + 2]);
    float p3 = __expf(s3 - mrun[r*16 + g*4 + 3]);
    float q0 = p0, q1 = p1, q2 = p2, q3 = p3;
#pragma unroll
    for (int msk = 1; msk <= 8; msk <<= 1){
      q0 += __shfl_xor(q0, msk);
      q1 += __shfl_xor(q1, msk);
      q2 += __shfl_xor(q2, msk);
      q3 += __shfl_xor(q3, msk);
    }
    if (l15 == 0){
      reds[c][r*16 + g*4 + 0] = q0;
      reds[c][r*16 + g*4 + 1] = q1;
      reds[c][r*16 + g*4 + 2] = q2;
      reds[c][r*16 + g*4 + 3] = q3;
    }
    P_s[r*16 + g*4 + 0][c*16 + l15] = f2h(p0);
    P_s[r*16 + g*4 + 1][c*16 + l15] = f2h(p1);
    P_s[r*16 + g*4 + 2][c*16 + l15] = f2h(p2);
    P_s[r*16 + g*4 + 3][c*16 + l15] = f2h(p3);
    // rescale out-acc (rows nf*16 + g*4 + q)
#pragma unroll
    for (int nf = 0; nf < 4; ++nf){
      float rs0 = resc_s[nf*16 + g*4 + 0];
      float rs1 = resc_s[nf*16 + g*4 + 1];
      float rs2 = resc_s[nf*16 + g*4 + 2];
      float rs3 = resc_s[nf*16 + g*4 + 3];
#pragma unroll
      for (int ef = 0; ef < 4; ++ef){
        acc[nf][ef][0] *= rs0; acc[nf][ef][1] *= rs1;
        acc[nf][ef][2] *= rs2; acc[nf][ef][3] *= rs3;
      }
    }
    WAITVM(0);                 // cam(mt+1) DMA + bf landed (flew under S+SM)
    __syncthreads();                                   // B3
    if (t < 64) lrun[t] = lrun[t]*resc_s[t] + reds[0][t] + reds[1][t];
    // PV: A-frags from P_s, B from prefetched Vt regs
    f16x8 af[4];
#pragma unroll
    for (int nf = 0; nf < 4; ++nf)
      af[nf] = *(const f16x8*)&P_s[nf*16 + l15][g*8];
#pragma unroll
    for (int nf = 0; nf < 4; ++nf)
#pragma unroll
      for (int ef = 0; ef < 4; ++ef)
        acc[nf][ef] = mfmah(af[nf], bf[ef], acc[nf][ef]);
  }
#undef STAGECAM

  __syncthreads();    // final lrun visible
  float* Og = O + ((size_t)bz*NN + (size_t)nb*64)*DD;
#pragma unroll
  for (int nf = 0; nf < 4; ++nf){
    float i0 = 1.f / lrun[nf*16 + g*4 + 0];
    float i1 = 1.f / lrun[nf*16 + g*4 + 1];
    float i2 = 1.f / lrun[nf*16 + g*4 + 2];
    float i3 = 1.f / lrun[nf*16 + g*4 + 3];
#pragma unroll
    for (int ef = 0; ef < 4; ++ef){
      int col = w*64 + ef*16 + l15;
      Og[(size_t)(nf*16 + g*4 + 0)*DD + col] = acc[nf][ef][0] * i0;
      Og[(size_t)(nf*16 + g*4 + 1)*DD + col] = acc[nf][ef][1] * i1;
      Og[(size_t)(nf*16 + g*4 + 2)*DD + col] = acc[nf][ef][2] * i2;
      Og[(size_t)(nf*16 + g*4 + 3)*DD + col] = acc[nf][ef][3] * i3;
    }
  }
}

// ---------------------------------------------------------------------------
extern "C" void kernel_launch(void* const* d_in, const int* in_sizes, int n_in,
                              void* d_out, int out_size, void* d_ws, size_t ws_size,
                              hipStream_t stream) {
  const float* lidar  = (const float*)d_in[0];   // [B,N,D]
  const float* camera = (const float*)d_in[1];   // [B,M,D]
  const float* lconf  = (const float*)d_in[2];   // [B,N,1]
  // d_in[3] camera_confidence: unused by the reference
  const float* Wq = (const float*)d_in[4];
  const float* bq = (const float*)d_in[5];
  const float* Wk = (const float*)d_in[6];
  // d_in[7] bk: row-constant in scores -> softmax-invariant, dropped
  const float* Wv = (const float*)d_in[8];
  const float* bv = (const float*)d_in[9];
  float* out = (float*)d_out;                    // [B,N,D] f32

  // workspace layout (bytes)
  char* ws = (char*)d_ws;
  unsigned short* liH    = (unsigned short*)(ws + 0);         // [B,N,D] f16 16.8MB
  unsigned short* atH    = (unsigned short*)(ws + 16777216);  // [D,D]   f16 0.5MB
  unsigned short* wvH    = (unsigned short*)(ws + 17301504);  // [D,D]   f16 0.5MB
  float*          c2     = (float*)(ws + 17825792);           // [D]
  unsigned short* Th     = (unsigned short*)(ws + 134217728); // [B,N,D] f16 16.8MB
  unsigned short* camH   = (unsigned short*)(ws + 150994944); // [B,M,D] f16 16.8MB
  unsigned short* Vt     = (unsigned short*)(ws + 167772160); // [B,D,M] f16 16.8MB
  float*          svec   = (float*)(ws + 184549376);          // [B,M]

  // prep: c2 first (cam_prep consumes it), then fused camera pass
  c2_kernel<<<dim3(2), 256, 0, stream>>>(bq, Wk, c2);
  cam_prep<<<dim3(BB*MM/4), 256, 0, stream>>>(camera, c2, camH, svec);
  cvt16_kernel<<<dim3(2048), 256, 0, stream>>>(lidar,  liH,  BB*NN*DD/4);
  cvt16_kernel<<<dim3(256),  256, 0, stream>>>(Wv,     wvH,  DD*DD/4);
  at_kernel<<<dim3(16,16), 256, 0, stream>>>(Wq, Wk, atH);

  // T = lidar @ At^T  (f16) -> Th
  gemm_h128<0><<<dim3(DD/128, NN/128, BB), 256, 0, stream>>>(
      liH, (long)NN*DD, DD,  atH, 0, DD,
      Th, (long)NN*DD, DD, nullptr);

  // Vt[e,m] = Wv[e,:].cam[m,:] + bv[e]  (f16)
  gemm_h128<1><<<dim3(MM/128, DD/128, BB), 256, 0, stream>>>(
      wvH, 0, DD,  camH, (long)MM*DD, DD,
      Vt, (long)DD*MM, MM, bv);

  // fused scores+softmax+PV  (grid 32 n-blocks x 8 batches)
  flash_kernel<<<dim3(32, 8), 512, 0, stream>>>(
      Th, camH, Vt, lconf, svec, out);
}

// Round 13
// 202.446 us; speedup vs baseline: 1.3415x; 1.3415x over previous
//
#include <hip/hip_runtime.h>
#include <hip/hip_bf16.h>

#define BB 8
#define NN 2048
#define MM 2048
#define DD 512

typedef __attribute__((ext_vector_type(8))) _Float16 f16x8;
typedef __attribute__((ext_vector_type(4))) float f32x4;
typedef __attribute__((ext_vector_type(8))) unsigned short u16x8;

__device__ __forceinline__ unsigned short f2h(float x){
  union { _Float16 h; unsigned short u; } cv;
  cv.h = (_Float16)x;           // v_cvt_f16_f32, RTN-even
  return cv.u;
}
__device__ __forceinline__ float h2f(unsigned short u){
  union { unsigned short u; _Float16 h; } cv;
  cv.u = u;
  return (float)cv.h;
}
__device__ __forceinline__ f32x4 mfmah(f16x8 a, f16x8 b, f32x4 c){
  return __builtin_amdgcn_mfma_f32_16x16x32_f16(a, b, c, 0, 0, 0);
}

// async global->LDS, 16B per lane; LDS dest is wave-uniform base + lane*16
#define GLD16(gp, lp) __builtin_amdgcn_global_load_lds( \
    (const __attribute__((address_space(1))) void*)(gp), \
    (__attribute__((address_space(3))) void*)(lp), 16, 0, 0)

// wait until <= n vector-memory ops outstanding (lgkm/exp not waited)
#define WAITVM(n) __builtin_amdgcn_s_waitcnt(0xF70 | (n))

// batch->XCD swizzle: flat id f -> bz = f&7 (XCD presumed f%8), bijective
// (requires gridDim.z == 8)
__device__ __forceinline__ void swz_xyz(int& bn, int& bm, int& bz){
  int f = ((int)blockIdx.z * (int)gridDim.y + (int)blockIdx.y) * (int)gridDim.x
        + (int)blockIdx.x;
  bz = f & 7;
  int r = f >> 3;
  bn = r % (int)gridDim.x;
  bm = r / (int)gridDim.x;
}

// ---------------------------------------------------------------------------
// cvt16: f32 -> f16, float4-vectorized, grid-stride
// ---------------------------------------------------------------------------
__global__ __launch_bounds__(256) void cvt16_kernel(const float* __restrict__ in,
    unsigned short* __restrict__ out, int n4){
  int i = blockIdx.x*256 + threadIdx.x;
  const int stride = gridDim.x*256;
  for (; i < n4; i += stride){
    float4 v = ((const float4*)in)[i];
    ushort4 h; h.x=f2h(v.x); h.y=f2h(v.y); h.z=f2h(v.z); h.w=f2h(v.w);
    ((ushort4*)out)[i] = h;
  }
}

// ---------------------------------------------------------------------------
// cam_prep: one pass over camera f32 -> camH f16 AND svec[row] = cam.c2
// ---------------------------------------------------------------------------
__global__ __launch_bounds__(256) void cam_prep(const float* __restrict__ cam,
    const float* __restrict__ c2,
    unsigned short* __restrict__ camH,
    float* __restrict__ svec){
  const int t = threadIdx.x;
  const int l = t & 63;
  const size_t row = (size_t)blockIdx.x*4 + (t >> 6);
  const float4* r4 = (const float4*)(cam + row*DD);
  const float4* c4 = (const float4*)c2;
  float4 v0 = r4[l*2],   v1 = r4[l*2+1];
  float4 a0 = c4[l*2],   a1 = c4[l*2+1];
  float p = v0.x*a0.x + v0.y*a0.y + v0.z*a0.z + v0.w*a0.w
          + v1.x*a1.x + v1.y*a1.y + v1.z*a1.z + v1.w*a1.w;
  for (int o = 32; o; o >>= 1) p += __shfl_xor(p, o);
  if (l == 0) svec[row] = p;
  ushort4 h0; h0.x=f2h(v0.x); h0.y=f2h(v0.y); h0.z=f2h(v0.z); h0.w=f2h(v0.w);
  ushort4 h1; h1.x=f2h(v1.x); h1.y=f2h(v1.y); h1.z=f2h(v1.z); h1.w=f2h(v1.w);
  ushort4* dst = (ushort4*)(camH + row*DD);
  dst[l*2]   = h0;
  dst[l*2+1] = h1;
}

// ---------------------------------------------------------------------------
// K0: At[j][i] = sum_e Wq[e][i] * Wk[e][j], f32 accum, f16 out
// ---------------------------------------------------------------------------
__global__ __launch_bounds__(256) void at_kernel(const float* __restrict__ Wq,
                                                 const float* __restrict__ Wk,
                                                 unsigned short* __restrict__ atH){
  const int i0 = blockIdx.x * 32, j0 = blockIdx.y * 32;
  __shared__ float q_s[32][33];
  __shared__ float k_s[32][33];
  const int t = threadIdx.x;
  const int tx = t & 15, ty = t >> 4;
  float acc[2][2] = {{0.f,0.f},{0.f,0.f}};
  for (int e0 = 0; e0 < DD; e0 += 32){
    __syncthreads();
#pragma unroll
    for (int p = 0; p < 4; ++p){
      int idx = t + 256*p;
      int e = idx >> 5, c = idx & 31;
      q_s[e][c] = Wq[(size_t)(e0+e)*DD + i0 + c];
      k_s[e][c] = Wk[(size_t)(e0+e)*DD + j0 + c];
    }
    __syncthreads();
#pragma unroll 8
    for (int e = 0; e < 32; ++e){
      float q0 = q_s[e][2*tx], q1 = q_s[e][2*tx+1];
      float k0 = k_s[e][2*ty], k1 = k_s[e][2*ty+1];
      acc[0][0] += k0*q0; acc[0][1] += k0*q1;
      acc[1][0] += k1*q0; acc[1][1] += k1*q1;
    }
  }
#pragma unroll
  for (int a = 0; a < 2; ++a)
#pragma unroll
    for (int b = 0; b < 2; ++b)
      atH[(size_t)(j0 + 2*ty + a)*DD + i0 + 2*tx + b] = f2h(acc[a][b]);
}

// c2[d] = sum_e bq[e] * Wk[e][d]
__global__ __launch_bounds__(256) void c2_kernel(const float* __restrict__ bq,
                                                 const float* __restrict__ Wk,
                                                 float* __restrict__ c2){
  int d = blockIdx.x * 256 + threadIdx.x;
  float a = 0.f;
  for (int e = 0; e < DD; ++e) a += bq[e] * Wk[(size_t)e*DD + d];
  c2[d] = a;
}

// ---------------------------------------------------------------------------
// Plain f16 GEMM, BT form: O[row,col] = sum_k A[row,k]*B[col,k], f16 out.
// Block 128x128, 4 waves 2x2, wave 64x64 (4x4 frags of 16x16x32 f16).
// MODE 0: plain.  MODE 1: + bias[row].
// ---------------------------------------------------------------------------
template<int MODE>
__global__ __launch_bounds__(256) void gemm_h128(
    const unsigned short* __restrict__ Ag, long sA, int lda,
    const unsigned short* __restrict__ Bg, long sB, int ldb,
    unsigned short* __restrict__ O, long sO, int ldo,
    const float* __restrict__ bias)
{
  __shared__ __attribute__((aligned(16))) unsigned short Ah[128][40];
  __shared__ __attribute__((aligned(16))) unsigned short Bh[128][40];

  int bn, bm, bz; swz_xyz(bn, bm, bz);
  const int t = threadIdx.x;
  const int lane = t & 63, w = t >> 6;
  const int wrow = w >> 1, wcol = w & 1;
  const int lr = lane & 15, lk = (lane >> 4) << 3;

  f32x4 acc[4][4];
#pragma unroll
  for (int m = 0; m < 4; ++m)
#pragma unroll
    for (int n = 0; n < 4; ++n){ f32x4 z = {0.f,0.f,0.f,0.f}; acc[m][n] = z; }

  const unsigned short* Ap = Ag + (size_t)bz*(size_t)sA + ((size_t)bm*128)*(size_t)lda;
  const unsigned short* Bp = Bg + (size_t)bz*(size_t)sB + ((size_t)bn*128)*(size_t)ldb;

  const int sr = t >> 2;          // 0..63
  const int sc = (t & 3) * 8;

  for (int k0 = 0; k0 < DD; k0 += 32){
    __syncthreads();
#pragma unroll
    for (int p = 0; p < 2; ++p){
      int r = sr + 64*p;
      *(u16x8*)&Ah[r][sc] = *(const u16x8*)(Ap + (size_t)r*lda + k0 + sc);
      *(u16x8*)&Bh[r][sc] = *(const u16x8*)(Bp + (size_t)r*ldb + k0 + sc);
    }
    __syncthreads();

    f16x8 af[4], bf[4];
#pragma unroll
    for (int m = 0; m < 4; ++m) af[m] = *(const f16x8*)&Ah[wrow*64 + m*16 + lr][lk];
#pragma unroll
    for (int n = 0; n < 4; ++n) bf[n] = *(const f16x8*)&Bh[wcol*64 + n*16 + lr][lk];
#pragma unroll
    for (int m = 0; m < 4; ++m)
#pragma unroll
      for (int n = 0; n < 4; ++n)
        acc[m][n] = mfmah(af[m], bf[n], acc[m][n]);
  }

  const int orow = bm*128 + wrow*64;
  const int ocol = bn*128 + wcol*64;
#pragma unroll
  for (int m = 0; m < 4; ++m){
#pragma unroll
    for (int n = 0; n < 4; ++n){
      int col  = ocol + n*16 + lr;
      int row0 = orow + m*16 + ((lane >> 4) << 2);
#pragma unroll
      for (int r = 0; r < 4; ++r){
        int row = row0 + r;
        float v = acc[m][n][r];
        if constexpr (MODE == 1) v += bias[row];
        O[(size_t)bz*(size_t)sO + (size_t)row*ldo + col] = f2h(v);
      }
    }
  }
}

// ---------------------------------------------------------------------------
// scores f16 GEMM: O[row,col] = conf[row]*(sum_k T[row,k]*cam[col,k]+svec[col])
// f16 OUTPUT (halves write traffic; |logit| <~130 -> f16 err <=0.031 abs,
// ~3% per-weight, normalizes out -> absmax += ~0.01).
// Block 128(rows) x 256(cols), 8 waves (2 row x 4 col), wave tile 64x64
// (4x4 frags) -> acc 64 VGPR, under the 128-VGPR occupancy cliff.
// ---------------------------------------------------------------------------
__global__ __launch_bounds__(512) void gemm_scores(
    const unsigned short* __restrict__ Th, const unsigned short* __restrict__ camH,
    unsigned short* __restrict__ O,
    const float* __restrict__ conf, const float* __restrict__ svec)
{
  __shared__ __attribute__((aligned(16))) unsigned short Ah[128][40];
  __shared__ __attribute__((aligned(16))) unsigned short Bh[256][40];

  int bn, bm, bz; swz_xyz(bn, bm, bz);   // grid (8,16,8)
  const int t = threadIdx.x;             // 0..511
  const int lane = t & 63, w = t >> 6;   // 8 waves
  const int wrow = w >> 2, wcol = w & 3; // 2 x 4
  const int lr = lane & 15, lk = (lane >> 4) << 3;

  f32x4 acc[4][4];
#pragma unroll
  for (int m = 0; m < 4; ++m)
#pragma unroll
    for (int n = 0; n < 4; ++n){ f32x4 z = {0.f,0.f,0.f,0.f}; acc[m][n] = z; }

  const unsigned short* Ap = Th   + (size_t)bz*((size_t)NN*DD) + ((size_t)bm*128)*DD;
  const unsigned short* Bp = camH + (size_t)bz*((size_t)MM*DD) + ((size_t)bn*256)*DD;

  const int sr = t >> 2;          // 0..127
  const int sc = (t & 3) * 8;     // 0,8,16,24

  for (int k0 = 0; k0 < DD; k0 += 32){
    __syncthreads();
    *(u16x8*)&Ah[sr][sc] = *(const u16x8*)(Ap + (size_t)sr*DD + k0 + sc);
#pragma unroll
    for (int p = 0; p < 2; ++p){
      int r = sr + 128*p;
      *(u16x8*)&Bh[r][sc] = *(const u16x8*)(Bp + (size_t)r*DD + k0 + sc);
    }
    __syncthreads();

    f16x8 af[4], bf[4];
#pragma unroll
    for (int m = 0; m < 4; ++m) af[m] = *(const f16x8*)&Ah[wrow*64 + m*16 + lr][lk];
#pragma unroll
    for (int n = 0; n < 4; ++n) bf[n] = *(const f16x8*)&Bh[wcol*64 + n*16 + lr][lk];
#pragma unroll
    for (int m = 0; m < 4; ++m)
#pragma unroll
      for (int n = 0; n < 4; ++n)
        acc[m][n] = mfmah(af[m], bf[n], acc[m][n]);
  }

  const int orow0 = bm*128 + wrow*64;
  const int ocol0 = bn*256 + wcol*64;
  const size_t obase = (size_t)bz*((size_t)NN*MM);
#pragma unroll
  for (int m = 0; m < 4; ++m){
#pragma unroll
    for (int n = 0; n < 4; ++n){
      int col  = ocol0 + n*16 + lr;
      float sv = svec[bz*MM + col];
      int row0 = orow0 + m*16 + ((lane >> 4) << 2);
#pragma unroll
      for (int r = 0; r < 4; ++r){
        int row = row0 + r;
        O[obase + (size_t)row*MM + col]
            = f2h(conf[bz*NN + row] * (acc[m][n][r] + sv));
      }
    }
  }
}

// ---------------------------------------------------------------------------
// Row softmax over M=2048, f16 in-place.  One 256-thread block per row,
// 8 elems/thread (u16x8).
// ---------------------------------------------------------------------------
__global__ __launch_bounds__(256) void softmax_h(unsigned short* __restrict__ scores){
  const size_t row = blockIdx.x;
  unsigned short* pr = scores + row * (size_t)MM;
  const int t = threadIdx.x;

  u16x8 v = ((const u16x8*)pr)[t];
  float x[8];
#pragma unroll
  for (int j = 0; j < 8; ++j) x[j] = h2f(v[j]);

  float mx = x[0];
#pragma unroll
  for (int j = 1; j < 8; ++j) mx = fmaxf(mx, x[j]);
  for (int o = 32; o; o >>= 1) mx = fmaxf(mx, __shfl_xor(mx, o));
  __shared__ float red[4];
  if ((t & 63) == 0) red[t >> 6] = mx;
  __syncthreads();
  mx = fmaxf(fmaxf(red[0], red[1]), fmaxf(red[2], red[3]));

  float e[8], s = 0.f;
#pragma unroll
  for (int j = 0; j < 8; ++j){ e[j] = __expf(x[j] - mx); s += e[j]; }
  for (int o = 32; o; o >>= 1) s += __shfl_xor(s, o);
  __syncthreads();               // everyone done reading red[] (max phase)
  if ((t & 63) == 0) red[t >> 6] = s;
  __syncthreads();
  float inv = 1.f / (red[0] + red[1] + red[2] + red[3]);

  u16x8 pv;
#pragma unroll
  for (int j = 0; j < 8; ++j) pv[j] = f2h(e[j] * inv);
  ((u16x8*)pr)[t] = pv;
}

// ---------------------------------------------------------------------------
// PV GEMM v2: out[n,e] = sum_m P[n,m]*Vt[e,m].  Block 64(n) x 256(e),
// 8 waves 1x8, wave 64n x 32e (4x2 frags), BK=64 (32 iters).  P f16 packed
// at lda=MM.  2-phase pipeline: double-buffered linear LDS staged via
// global_load_lds w16; issue next tile's DMA BEFORE computing current;
// ONE raw s_barrier + vmcnt(0) per iter (DMA flies under compute).
// XOR chunk swizzle pc = lc ^ (row&7) on BOTH pre-swizzled per-lane global
// source and fragment reads (T21).
// ---------------------------------------------------------------------------
__global__ __launch_bounds__(512) void gemm_pv(
    const unsigned short* __restrict__ P,
    const unsigned short* __restrict__ V,
    float* __restrict__ O)
{
  __shared__ unsigned short Ah[2][64][64];    // 16 KB
  __shared__ unsigned short Bh[2][256][64];   // 64 KB

  int bn, bm, bz; swz_xyz(bn, bm, bz);   // grid (2,32,8)
  const int t = threadIdx.x;             // 0..511
  const int lane = t & 63, w = t >> 6;   // 8 waves
  const int lr = lane & 15, lc0 = lane >> 4;

  const unsigned short* Ap = P + (size_t)bz*((size_t)NN*MM) + ((size_t)bm*64)*MM;
  const unsigned short* Bp = V + (size_t)bz*((size_t)DD*MM) + ((size_t)bn*256)*MM;

  // staging: wave w stages A rows 8w..8w+7 (1 instr) and B rows 32w..32w+31
  // (4 instrs).  lane i -> row base+(i>>3), phys chunk i&7; its global source
  // is logical chunk (i&7)^(row&7)  (inverse swizzle; XOR is an involution).
  const int arow = 8*w + (lane >> 3);
  const int alc  = (lane & 7) ^ (arow & 7);
  const unsigned short* gA = Ap + (size_t)arow*MM + alc*8;
  const int brow = 32*w + (lane >> 3);
  const int blc  = (lane & 7) ^ (brow & 7);   // same for all 4 B instrs (rows +8k)
  const unsigned short* gB = Bp + (size_t)brow*MM + blc*8;

#define PV_STAGE(bufi, kofs) do {                                   \
    GLD16(gA + (kofs),                 &Ah[bufi][8*w][0]);          \
    GLD16(gB + (kofs),                 &Bh[bufi][32*w     ][0]);    \
    GLD16(gB + (kofs) + (size_t)8*MM,  &Bh[bufi][32*w +  8][0]);    \
    GLD16(gB + (kofs) + (size_t)16*MM, &Bh[bufi][32*w + 16][0]);    \
    GLD16(gB + (kofs) + (size_t)24*MM, &Bh[bufi][32*w + 24][0]);    \
  } while(0)

  f32x4 acc[4][2];
#pragma unroll
  for (int m = 0; m < 4; ++m)
#pragma unroll
    for (int n = 0; n < 2; ++n){ f32x4 z = {0.f,0.f,0.f,0.f}; acc[m][n] = z; }

  // prologue: stage tile 0, wait, sync
  PV_STAGE(0, 0);
  WAITVM(0);
  __builtin_amdgcn_s_barrier();
  __builtin_amdgcn_sched_barrier(0);

  for (int tt = 0; tt < 32; ++tt){
    const int buf = tt & 1;
    if (tt < 31) PV_STAGE(buf^1, (size_t)(tt+1)*64);  // overwrites buffer
                                                      // computed at tt-1; all
                                                      // waves passed tt-1's
                                                      // end barrier -> safe
    f16x8 af[4][2], bf[2][2];
#pragma unroll
    for (int m = 0; m < 4; ++m){
      int row = m*16 + lr;
#pragma unroll
      for (int ks = 0; ks < 2; ++ks){
        int pc = (ks*4 + lc0) ^ (row & 7);
        af[m][ks] = *(const f16x8*)&Ah[buf][row][pc*8];
      }
    }
#pragma unroll
    for (int n = 0; n < 2; ++n){
      int row = w*32 + n*16 + lr;
#pragma unroll
      for (int ks = 0; ks < 2; ++ks){
        int pc = (ks*4 + lc0) ^ (row & 7);
        bf[n][ks] = *(const f16x8*)&Bh[buf][row][pc*8];
      }
    }
    __builtin_amdgcn_s_setprio(1);
#pragma unroll
    for (int m = 0; m < 4; ++m)
#pragma unroll
      for (int n = 0; n < 2; ++n){
        acc[m][n] = mfmah(af[m][0], bf[n][0], acc[m][n]);
        acc[m][n] = mfmah(af[m][1], bf[n][1], acc[m][n]);
      }
    __builtin_amdgcn_s_setprio(0);

    WAITVM(0);                          // this iter's DMA landed (flew under
    __builtin_amdgcn_s_barrier();       // the MFMA phase, not serialized)
    __builtin_amdgcn_sched_barrier(0);
  }
#undef PV_STAGE

  const int orow0 = bm*64;
  const int ocol0 = bn*256 + w*32;
#pragma unroll
  for (int m = 0; m < 4; ++m){
#pragma unroll
    for (int n = 0; n < 2; ++n){
      int col  = ocol0 + n*16 + lr;
      int row0 = orow0 + m*16 + ((lane >> 4) << 2);
#pragma unroll
      for (int r = 0; r < 4; ++r){
        int row = row0 + r;
        O[(size_t)bz*((size_t)NN*DD) + (size_t)row*DD + col] = acc[m][n][r];
      }
    }
  }
}

// ---------------------------------------------------------------------------
extern "C" void kernel_launch(void* const* d_in, const int* in_sizes, int n_in,
                              void* d_out, int out_size, void* d_ws, size_t ws_size,
                              hipStream_t stream) {
  const float* lidar  = (const float*)d_in[0];   // [B,N,D]
  const float* camera = (const float*)d_in[1];   // [B,M,D]
  const float* lconf  = (const float*)d_in[2];   // [B,N,1]
  // d_in[3] camera_confidence: unused by the reference
  const float* Wq = (const float*)d_in[4];
  const float* bq = (const float*)d_in[5];
  const float* Wk = (const float*)d_in[6];
  // d_in[7] bk: row-constant in scores -> softmax-invariant, dropped
  const float* Wv = (const float*)d_in[8];
  const float* bv = (const float*)d_in[9];
  float* out = (float*)d_out;                    // [B,N,D] f32

  // workspace layout (bytes)
  char* ws = (char*)d_ws;
  unsigned short* scores = (unsigned short*)(ws + 0);         // [B,N,M] f16 67.1MB (P in place)
  // transient aliases inside scores region (dead before scores is written):
  unsigned short* liH    = (unsigned short*)(ws + 0);         // [B,N,D] f16 16.8MB
  unsigned short* atH    = (unsigned short*)(ws + 16777216);  // [D,D]   f16 0.5MB
  unsigned short* wvH    = (unsigned short*)(ws + 17301504);  // [D,D]   f16 0.5MB
  float*          c2     = (float*)(ws + 17825792);           // [D]
  // persistent:
  unsigned short* Th     = (unsigned short*)(ws + 134217728); // [B,N,D] f16 16.8MB
  unsigned short* camH   = (unsigned short*)(ws + 150994944); // [B,M,D] f16 16.8MB
  unsigned short* Vt     = (unsigned short*)(ws + 167772160); // [B,D,M] f16 16.8MB
  float*          svec   = (float*)(ws + 184549376);          // [B,M]

  // prep: c2 first (cam_prep consumes it), then fused camera pass
  c2_kernel<<<dim3(2), 256, 0, stream>>>(bq, Wk, c2);
  cam_prep<<<dim3(BB*MM/4), 256, 0, stream>>>(camera, c2, camH, svec);
  cvt16_kernel<<<dim3(2048), 256, 0, stream>>>(lidar,  liH,  BB*NN*DD/4);
  cvt16_kernel<<<dim3(256),  256, 0, stream>>>(Wv,     wvH,  DD*DD/4);
  at_kernel<<<dim3(16,16), 256, 0, stream>>>(Wq, Wk, atH);

  // T = lidar @ At^T  (f16) -> Th
  gemm_h128<0><<<dim3(DD/128, NN/128, BB), 256, 0, stream>>>(
      liH, (long)NN*DD, DD,  atH, 0, DD,
      Th, (long)NN*DD, DD, nullptr);

  // Vt[e,m] = Wv[e,:].cam[m,:] + bv[e]  (f16)
  gemm_h128<1><<<dim3(MM/128, DD/128, BB), 256, 0, stream>>>(
      wvH, 0, DD,  camH, (long)MM*DD, DD,
      Vt, (long)DD*MM, MM, bv);

  // scores = conf * (T @ cam^T + svec)  (f16 inputs, f16 out, 8-wave)
  gemm_scores<<<dim3(MM/256, NN/128, BB), 512, 0, stream>>>(
      Th, camH, scores, lconf, svec);

  // row softmax, f16 in-place
  softmax_h<<<dim3(BB*NN), 256, 0, stream>>>(scores);

  // out = P @ Vt^T  (f16, 8-wave, 2-phase pipelined)
  gemm_pv<<<dim3(DD/256, NN/64, BB), 512, 0, stream>>>(
      scores, Vt, out);
}

// Round 14
// 199.083 us; speedup vs baseline: 1.3642x; 1.0169x over previous
//
#include <hip/hip_runtime.h>
#include <hip/hip_bf16.h>

#define BB 8
#define NN 2048
#define MM 2048
#define DD 512

typedef __attribute__((ext_vector_type(8))) _Float16 f16x8;
typedef __attribute__((ext_vector_type(4))) float f32x4;
typedef __attribute__((ext_vector_type(8))) unsigned short u16x8;

__device__ __forceinline__ unsigned short f2h(float x){
  union { _Float16 h; unsigned short u; } cv;
  cv.h = (_Float16)x;           // v_cvt_f16_f32, RTN-even
  return cv.u;
}
__device__ __forceinline__ float h2f(unsigned short u){
  union { unsigned short u; _Float16 h; } cv;
  cv.u = u;
  return (float)cv.h;
}
__device__ __forceinline__ f32x4 mfmah(f16x8 a, f16x8 b, f32x4 c){
  return __builtin_amdgcn_mfma_f32_16x16x32_f16(a, b, c, 0, 0, 0);
}

// async global->LDS, 16B per lane; LDS dest is wave-uniform base + lane*16
#define GLD16(gp, lp) __builtin_amdgcn_global_load_lds( \
    (const __attribute__((address_space(1))) void*)(gp), \
    (__attribute__((address_space(3))) void*)(lp), 16, 0, 0)

// wait until <= n vector-memory ops outstanding (lgkm/exp not waited)
#define WAITVM(n) __builtin_amdgcn_s_waitcnt(0xF70 | (n))

// batch->XCD swizzle: flat id f -> bz = f&7 (XCD presumed f%8), bijective
// (requires gridDim.z == 8)
__device__ __forceinline__ void swz_xyz(int& bn, int& bm, int& bz){
  int f = ((int)blockIdx.z * (int)gridDim.y + (int)blockIdx.y) * (int)gridDim.x
        + (int)blockIdx.x;
  bz = f & 7;
  int r = f >> 3;
  bn = r % (int)gridDim.x;
  bm = r / (int)gridDim.x;
}

// ---------------------------------------------------------------------------
// cvt16: f32 -> f16, float4-vectorized, grid-stride
// ---------------------------------------------------------------------------
__global__ __launch_bounds__(256) void cvt16_kernel(const float* __restrict__ in,
    unsigned short* __restrict__ out, int n4){
  int i = blockIdx.x*256 + threadIdx.x;
  const int stride = gridDim.x*256;
  for (; i < n4; i += stride){
    float4 v = ((const float4*)in)[i];
    ushort4 h; h.x=f2h(v.x); h.y=f2h(v.y); h.z=f2h(v.z); h.w=f2h(v.w);
    ((ushort4*)out)[i] = h;
  }
}

// ---------------------------------------------------------------------------
// cam_prep: one pass over camera f32 -> camH f16 AND svec[row] = cam.c2
// ---------------------------------------------------------------------------
__global__ __launch_bounds__(256) void cam_prep(const float* __restrict__ cam,
    const float* __restrict__ c2,
    unsigned short* __restrict__ camH,
    float* __restrict__ svec){
  const int t = threadIdx.x;
  const int l = t & 63;
  const size_t row = (size_t)blockIdx.x*4 + (t >> 6);
  const float4* r4 = (const float4*)(cam + row*DD);
  const float4* c4 = (const float4*)c2;
  float4 v0 = r4[l*2],   v1 = r4[l*2+1];
  float4 a0 = c4[l*2],   a1 = c4[l*2+1];
  float p = v0.x*a0.x + v0.y*a0.y + v0.z*a0.z + v0.w*a0.w
          + v1.x*a1.x + v1.y*a1.y + v1.z*a1.z + v1.w*a1.w;
  for (int o = 32; o; o >>= 1) p += __shfl_xor(p, o);
  if (l == 0) svec[row] = p;
  ushort4 h0; h0.x=f2h(v0.x); h0.y=f2h(v0.y); h0.z=f2h(v0.z); h0.w=f2h(v0.w);
  ushort4 h1; h1.x=f2h(v1.x); h1.y=f2h(v1.y); h1.z=f2h(v1.z); h1.w=f2h(v1.w);
  ushort4* dst = (ushort4*)(camH + row*DD);
  dst[l*2]   = h0;
  dst[l*2+1] = h1;
}

// ---------------------------------------------------------------------------
// K0: At[j][i] = sum_e Wq[e][i] * Wk[e][j], f32 accum, f16 out
// ---------------------------------------------------------------------------
__global__ __launch_bounds__(256) void at_kernel(const float* __restrict__ Wq,
                                                 const float* __restrict__ Wk,
                                                 unsigned short* __restrict__ atH){
  const int i0 = blockIdx.x * 32, j0 = blockIdx.y * 32;
  __shared__ float q_s[32][33];
  __shared__ float k_s[32][33];
  const int t = threadIdx.x;
  const int tx = t & 15, ty = t >> 4;
  float acc[2][2] = {{0.f,0.f},{0.f,0.f}};
  for (int e0 = 0; e0 < DD; e0 += 32){
    __syncthreads();
#pragma unroll
    for (int p = 0; p < 4; ++p){
      int idx = t + 256*p;
      int e = idx >> 5, c = idx & 31;
      q_s[e][c] = Wq[(size_t)(e0+e)*DD + i0 + c];
      k_s[e][c] = Wk[(size_t)(e0+e)*DD + j0 + c];
    }
    __syncthreads();
#pragma unroll 8
    for (int e = 0; e < 32; ++e){
      float q0 = q_s[e][2*tx], q1 = q_s[e][2*tx+1];
      float k0 = k_s[e][2*ty], k1 = k_s[e][2*ty+1];
      acc[0][0] += k0*q0; acc[0][1] += k0*q1;
      acc[1][0] += k1*q0; acc[1][1] += k1*q1;
    }
  }
#pragma unroll
  for (int a = 0; a < 2; ++a)
#pragma unroll
    for (int b = 0; b < 2; ++b)
      atH[(size_t)(j0 + 2*ty + a)*DD + i0 + 2*tx + b] = f2h(acc[a][b]);
}

// c2[d] = sum_e bq[e] * Wk[e][d]
__global__ __launch_bounds__(256) void c2_kernel(const float* __restrict__ bq,
                                                 const float* __restrict__ Wk,
                                                 float* __restrict__ c2){
  int d = blockIdx.x * 256 + threadIdx.x;
  float a = 0.f;
  for (int e = 0; e < DD; ++e) a += bq[e] * Wk[(size_t)e*DD + d];
  c2[d] = a;
}

// ---------------------------------------------------------------------------
// Plain f16 GEMM, BT form: O[row,col] = sum_k A[row,k]*B[col,k], f16 out.
// Block 128x128, 4 waves 2x2, wave 64x64 (4x4 frags of 16x16x32 f16).
// MODE 0: plain.  MODE 1: + bias[row].
// ---------------------------------------------------------------------------
template<int MODE>
__global__ __launch_bounds__(256) void gemm_h128(
    const unsigned short* __restrict__ Ag, long sA, int lda,
    const unsigned short* __restrict__ Bg, long sB, int ldb,
    unsigned short* __restrict__ O, long sO, int ldo,
    const float* __restrict__ bias)
{
  __shared__ __attribute__((aligned(16))) unsigned short Ah[128][40];
  __shared__ __attribute__((aligned(16))) unsigned short Bh[128][40];

  int bn, bm, bz; swz_xyz(bn, bm, bz);
  const int t = threadIdx.x;
  const int lane = t & 63, w = t >> 6;
  const int wrow = w >> 1, wcol = w & 1;
  const int lr = lane & 15, lk = (lane >> 4) << 3;

  f32x4 acc[4][4];
#pragma unroll
  for (int m = 0; m < 4; ++m)
#pragma unroll
    for (int n = 0; n < 4; ++n){ f32x4 z = {0.f,0.f,0.f,0.f}; acc[m][n] = z; }

  const unsigned short* Ap = Ag + (size_t)bz*(size_t)sA + ((size_t)bm*128)*(size_t)lda;
  const unsigned short* Bp = Bg + (size_t)bz*(size_t)sB + ((size_t)bn*128)*(size_t)ldb;

  const int sr = t >> 2;          // 0..63
  const int sc = (t & 3) * 8;

  for (int k0 = 0; k0 < DD; k0 += 32){
    __syncthreads();
#pragma unroll
    for (int p = 0; p < 2; ++p){
      int r = sr + 64*p;
      *(u16x8*)&Ah[r][sc] = *(const u16x8*)(Ap + (size_t)r*lda + k0 + sc);
      *(u16x8*)&Bh[r][sc] = *(const u16x8*)(Bp + (size_t)r*ldb + k0 + sc);
    }
    __syncthreads();

    f16x8 af[4], bf[4];
#pragma unroll
    for (int m = 0; m < 4; ++m) af[m] = *(const f16x8*)&Ah[wrow*64 + m*16 + lr][lk];
#pragma unroll
    for (int n = 0; n < 4; ++n) bf[n] = *(const f16x8*)&Bh[wcol*64 + n*16 + lr][lk];
#pragma unroll
    for (int m = 0; m < 4; ++m)
#pragma unroll
      for (int n = 0; n < 4; ++n)
        acc[m][n] = mfmah(af[m], bf[n], acc[m][n]);
  }

  const int orow = bm*128 + wrow*64;
  const int ocol = bn*128 + wcol*64;
#pragma unroll
  for (int m = 0; m < 4; ++m){
#pragma unroll
    for (int n = 0; n < 4; ++n){
      int col  = ocol + n*16 + lr;
      int row0 = orow + m*16 + ((lane >> 4) << 2);
#pragma unroll
      for (int r = 0; r < 4; ++r){
        int row = row0 + r;
        float v = acc[m][n][r];
        if constexpr (MODE == 1) v += bias[row];
        O[(size_t)bz*(size_t)sO + (size_t)row*ldo + col] = f2h(v);
      }
    }
  }
}

// ---------------------------------------------------------------------------
// scores f16 GEMM v2 (PV-style 2-phase pipeline):
//   O[row,col] = f2h( conf[row]*(sum_k T[row,k]*cam[col,k] + svec[col]) )
// Block 128(rows) x 256(cols), 8 waves (2x4), wave 64x64 (4x4 frags),
// BK=32, 16 K-steps.  Double-buffered LINEAR LDS (48 KB) staged via
// global_load_lds w16; issue next tile's DMA BEFORE the MFMA cluster;
// ONE vmcnt(0)+s_barrier per iter.  XOR chunk swizzle pc = lc ^ (row&3)
// on BOTH pre-swizzled per-lane source and fragment reads (T21); 16-lane
// read groups spread over 8 bank-quads at 2-way (free, m136).
// ---------------------------------------------------------------------------
__global__ __launch_bounds__(512) void gemm_scores(
    const unsigned short* __restrict__ Th, const unsigned short* __restrict__ camH,
    unsigned short* __restrict__ O,
    const float* __restrict__ conf, const float* __restrict__ svec)
{
  __shared__ unsigned short Ah[2][128][32];   // 16 KB
  __shared__ unsigned short Bh[2][256][32];   // 32 KB

  int bn, bm, bz; swz_xyz(bn, bm, bz);   // grid (8,16,8)
  const int t = threadIdx.x;             // 0..511
  const int lane = t & 63, w = t >> 6;   // 8 waves
  const int wrow = w >> 2, wcol = w & 3; // 2 x 4
  const int lr = lane & 15;
  const int c4 = lane >> 4;              // read chunk index 0..3

  const unsigned short* Ap = Th   + (size_t)bz*((size_t)NN*DD) + ((size_t)bm*128)*DD;
  const unsigned short* Bp = camH + (size_t)bz*((size_t)MM*DD) + ((size_t)bn*256)*DD;

  // staging: wave w stages A rows [16w,16w+16) (1 instr) and B rows
  // [32w,32w+32) (2 instrs of 16 rows).  lane i -> row base+(i>>2), phys
  // chunk (i&3); global source = logical chunk (i&3)^(row&3) (inverse swz;
  // XOR involution).  (row+16)&3 == row&3 -> same source col for B instr 2.
  const int sar  = w*16 + (lane >> 2);
  const int salc = (lane & 3) ^ (sar & 3);
  const unsigned short* gA = Ap + (size_t)sar*DD + salc*8;
  const int sbr  = w*32 + (lane >> 2);
  const int sblc = (lane & 3) ^ (sbr & 3);
  const unsigned short* gB = Bp + (size_t)sbr*DD + sblc*8;

#define SC_STAGE(bufi, kofs) do {                                  \
    GLD16(gA + (kofs),                 &Ah[bufi][w*16     ][0]);   \
    GLD16(gB + (kofs),                 &Bh[bufi][w*32     ][0]);   \
    GLD16(gB + (kofs) + (size_t)16*DD, &Bh[bufi][w*32 + 16][0]);   \
  } while(0)

  f32x4 acc[4][4];
#pragma unroll
  for (int m = 0; m < 4; ++m)
#pragma unroll
    for (int n = 0; n < 4; ++n){ f32x4 z = {0.f,0.f,0.f,0.f}; acc[m][n] = z; }

  // prologue
  SC_STAGE(0, 0);
  WAITVM(0);
  __builtin_amdgcn_s_barrier();
  __builtin_amdgcn_sched_barrier(0);

  for (int tt = 0; tt < 16; ++tt){
    const int buf = tt & 1;
    if (tt < 15) SC_STAGE(buf^1, (size_t)(tt+1)*32);  // buf^1 computed at
                                                      // tt-1; all waves past
                                                      // tt-1's end barrier
    f16x8 af[4], bf[4];
#pragma unroll
    for (int m = 0; m < 4; ++m){
      int row = wrow*64 + m*16 + lr;
      int pc  = c4 ^ (row & 3);
      af[m] = *(const f16x8*)&Ah[buf][row][pc*8];
    }
#pragma unroll
    for (int n = 0; n < 4; ++n){
      int row = wcol*64 + n*16 + lr;
      int pc  = c4 ^ (row & 3);
      bf[n] = *(const f16x8*)&Bh[buf][row][pc*8];
    }
    __builtin_amdgcn_s_setprio(1);
#pragma unroll
    for (int m = 0; m < 4; ++m)
#pragma unroll
      for (int n = 0; n < 4; ++n)
        acc[m][n] = mfmah(af[m], bf[n], acc[m][n]);
    __builtin_amdgcn_s_setprio(0);

    WAITVM(0);                          // next tile's DMA landed (flew under
    __builtin_amdgcn_s_barrier();       // the MFMA phase)
    __builtin_amdgcn_sched_barrier(0);
  }
#undef SC_STAGE

  const int orow0 = bm*128 + wrow*64;
  const int ocol0 = bn*256 + wcol*64;
  const size_t obase = (size_t)bz*((size_t)NN*MM);
#pragma unroll
  for (int m = 0; m < 4; ++m){
#pragma unroll
    for (int n = 0; n < 4; ++n){
      int col  = ocol0 + n*16 + lr;
      float sv = svec[bz*MM + col];
      int row0 = orow0 + m*16 + ((lane >> 4) << 2);
#pragma unroll
      for (int r = 0; r < 4; ++r){
        int row = row0 + r;
        O[obase + (size_t)row*MM + col]
            = f2h(conf[bz*NN + row] * (acc[m][n][r] + sv));
      }
    }
  }
}

// ---------------------------------------------------------------------------
// Row softmax over M=2048, f16 in-place.  One 256-thread block per row,
// 8 elems/thread (u16x8).
// ---------------------------------------------------------------------------
__global__ __launch_bounds__(256) void softmax_h(unsigned short* __restrict__ scores){
  const size_t row = blockIdx.x;
  unsigned short* pr = scores + row * (size_t)MM;
  const int t = threadIdx.x;

  u16x8 v = ((const u16x8*)pr)[t];
  float x[8];
#pragma unroll
  for (int j = 0; j < 8; ++j) x[j] = h2f(v[j]);

  float mx = x[0];
#pragma unroll
  for (int j = 1; j < 8; ++j) mx = fmaxf(mx, x[j]);
  for (int o = 32; o; o >>= 1) mx = fmaxf(mx, __shfl_xor(mx, o));
  __shared__ float red[4];
  if ((t & 63) == 0) red[t >> 6] = mx;
  __syncthreads();
  mx = fmaxf(fmaxf(red[0], red[1]), fmaxf(red[2], red[3]));

  float e[8], s = 0.f;
#pragma unroll
  for (int j = 0; j < 8; ++j){ e[j] = __expf(x[j] - mx); s += e[j]; }
  for (int o = 32; o; o >>= 1) s += __shfl_xor(s, o);
  __syncthreads();               // everyone done reading red[] (max phase)
  if ((t & 63) == 0) red[t >> 6] = s;
  __syncthreads();
  float inv = 1.f / (red[0] + red[1] + red[2] + red[3]);

  u16x8 pv;
#pragma unroll
  for (int j = 0; j < 8; ++j) pv[j] = f2h(e[j] * inv);
  ((u16x8*)pr)[t] = pv;
}

// ---------------------------------------------------------------------------
// PV GEMM v2: out[n,e] = sum_m P[n,m]*Vt[e,m].  Block 64(n) x 256(e),
// 8 waves 1x8, wave 64n x 32e (4x2 frags), BK=64 (32 iters).  P f16 packed
// at lda=MM.  2-phase pipeline: double-buffered linear LDS staged via
// global_load_lds w16; issue next tile's DMA BEFORE computing current;
// ONE raw s_barrier + vmcnt(0) per iter (DMA flies under compute).
// XOR chunk swizzle pc = lc ^ (row&7) on BOTH pre-swizzled per-lane global
// source and fragment reads (T21).
// ---------------------------------------------------------------------------
__global__ __launch_bounds__(512) void gemm_pv(
    const unsigned short* __restrict__ P,
    const unsigned short* __restrict__ V,
    float* __restrict__ O)
{
  __shared__ unsigned short Ah[2][64][64];    // 16 KB
  __shared__ unsigned short Bh[2][256][64];   // 64 KB

  int bn, bm, bz; swz_xyz(bn, bm, bz);   // grid (2,32,8)
  const int t = threadIdx.x;             // 0..511
  const int lane = t & 63, w = t >> 6;   // 8 waves
  const int lr = lane & 15, lc0 = lane >> 4;

  const unsigned short* Ap = P + (size_t)bz*((size_t)NN*MM) + ((size_t)bm*64)*MM;
  const unsigned short* Bp = V + (size_t)bz*((size_t)DD*MM) + ((size_t)bn*256)*MM;

  // staging: wave w stages A rows 8w..8w+7 (1 instr) and B rows 32w..32w+31
  // (4 instrs).  lane i -> row base+(i>>3), phys chunk i&7; its global source
  // is logical chunk (i&7)^(row&7)  (inverse swizzle; XOR is an involution).
  const int arow = 8*w + (lane >> 3);
  const int alc  = (lane & 7) ^ (arow & 7);
  const unsigned short* gA = Ap + (size_t)arow*MM + alc*8;
  const int brow = 32*w + (lane >> 3);
  const int blc  = (lane & 7) ^ (brow & 7);   // same for all 4 B instrs (rows +8k)
  const unsigned short* gB = Bp + (size_t)brow*MM + blc*8;

#define PV_STAGE(bufi, kofs) do {                                   \
    GLD16(gA + (kofs),                 &Ah[bufi][8*w][0]);          \
    GLD16(gB + (kofs),                 &Bh[bufi][32*w     ][0]);    \
    GLD16(gB + (kofs) + (size_t)8*MM,  &Bh[bufi][32*w +  8][0]);    \
    GLD16(gB + (kofs) + (size_t)16*MM, &Bh[bufi][32*w + 16][0]);    \
    GLD16(gB + (kofs) + (size_t)24*MM, &Bh[bufi][32*w + 24][0]);    \
  } while(0)

  f32x4 acc[4][2];
#pragma unroll
  for (int m = 0; m < 4; ++m)
#pragma unroll
    for (int n = 0; n < 2; ++n){ f32x4 z = {0.f,0.f,0.f,0.f}; acc[m][n] = z; }

  // prologue: stage tile 0, wait, sync
  PV_STAGE(0, 0);
  WAITVM(0);
  __builtin_amdgcn_s_barrier();
  __builtin_amdgcn_sched_barrier(0);

  for (int tt = 0; tt < 32; ++tt){
    const int buf = tt & 1;
    if (tt < 31) PV_STAGE(buf^1, (size_t)(tt+1)*64);  // overwrites buffer
                                                      // computed at tt-1; all
                                                      // waves passed tt-1's
                                                      // end barrier -> safe
    f16x8 af[4][2], bf[2][2];
#pragma unroll
    for (int m = 0; m < 4; ++m){
      int row = m*16 + lr;
#pragma unroll
      for (int ks = 0; ks < 2; ++ks){
        int pc = (ks*4 + lc0) ^ (row & 7);
        af[m][ks] = *(const f16x8*)&Ah[buf][row][pc*8];
      }
    }
#pragma unroll
    for (int n = 0; n < 2; ++n){
      int row = w*32 + n*16 + lr;
#pragma unroll
      for (int ks = 0; ks < 2; ++ks){
        int pc = (ks*4 + lc0) ^ (row & 7);
        bf[n][ks] = *(const f16x8*)&Bh[buf][row][pc*8];
      }
    }
    __builtin_amdgcn_s_setprio(1);
#pragma unroll
    for (int m = 0; m < 4; ++m)
#pragma unroll
      for (int n = 0; n < 2; ++n){
        acc[m][n] = mfmah(af[m][0], bf[n][0], acc[m][n]);
        acc[m][n] = mfmah(af[m][1], bf[n][1], acc[m][n]);
      }
    __builtin_amdgcn_s_setprio(0);

    WAITVM(0);                          // this iter's DMA landed (flew under
    __builtin_amdgcn_s_barrier();       // the MFMA phase, not serialized)
    __builtin_amdgcn_sched_barrier(0);
  }
#undef PV_STAGE

  const int orow0 = bm*64;
  const int ocol0 = bn*256 + w*32;
#pragma unroll
  for (int m = 0; m < 4; ++m){
#pragma unroll
    for (int n = 0; n < 2; ++n){
      int col  = ocol0 + n*16 + lr;
      int row0 = orow0 + m*16 + ((lane >> 4) << 2);
#pragma unroll
      for (int r = 0; r < 4; ++r){
        int row = row0 + r;
        O[(size_t)bz*((size_t)NN*DD) + (size_t)row*DD + col] = acc[m][n][r];
      }
    }
  }
}

// ---------------------------------------------------------------------------
extern "C" void kernel_launch(void* const* d_in, const int* in_sizes, int n_in,
                              void* d_out, int out_size, void* d_ws, size_t ws_size,
                              hipStream_t stream) {
  const float* lidar  = (const float*)d_in[0];   // [B,N,D]
  const float* camera = (const float*)d_in[1];   // [B,M,D]
  const float* lconf  = (const float*)d_in[2];   // [B,N,1]
  // d_in[3] camera_confidence: unused by the reference
  const float* Wq = (const float*)d_in[4];
  const float* bq = (const float*)d_in[5];
  const float* Wk = (const float*)d_in[6];
  // d_in[7] bk: row-constant in scores -> softmax-invariant, dropped
  const float* Wv = (const float*)d_in[8];
  const float* bv = (const float*)d_in[9];
  float* out = (float*)d_out;                    // [B,N,D] f32

  // workspace layout (bytes)
  char* ws = (char*)d_ws;
  unsigned short* scores = (unsigned short*)(ws + 0);         // [B,N,M] f16 67.1MB (P in place)
  // transient aliases inside scores region (dead before scores is written):
  unsigned short* liH    = (unsigned short*)(ws + 0);         // [B,N,D] f16 16.8MB
  unsigned short* atH    = (unsigned short*)(ws + 16777216);  // [D,D]   f16 0.5MB
  unsigned short* wvH    = (unsigned short*)(ws + 17301504);  // [D,D]   f16 0.5MB
  float*          c2     = (float*)(ws + 17825792);           // [D]
  // persistent:
  unsigned short* Th     = (unsigned short*)(ws + 134217728); // [B,N,D] f16 16.8MB
  unsigned short* camH   = (unsigned short*)(ws + 150994944); // [B,M,D] f16 16.8MB
  unsigned short* Vt     = (unsigned short*)(ws + 167772160); // [B,D,M] f16 16.8MB
  float*          svec   = (float*)(ws + 184549376);          // [B,M]

  // prep: c2 first (cam_prep consumes it), then fused camera pass
  c2_kernel<<<dim3(2), 256, 0, stream>>>(bq, Wk, c2);
  cam_prep<<<dim3(BB*MM/4), 256, 0, stream>>>(camera, c2, camH, svec);
  cvt16_kernel<<<dim3(2048), 256, 0, stream>>>(lidar,  liH,  BB*NN*DD/4);
  cvt16_kernel<<<dim3(256),  256, 0, stream>>>(Wv,     wvH,  DD*DD/4);
  at_kernel<<<dim3(16,16), 256, 0, stream>>>(Wq, Wk, atH);

  // T = lidar @ At^T  (f16) -> Th
  gemm_h128<0><<<dim3(DD/128, NN/128, BB), 256, 0, stream>>>(
      liH, (long)NN*DD, DD,  atH, 0, DD,
      Th, (long)NN*DD, DD, nullptr);

  // Vt[e,m] = Wv[e,:].cam[m,:] + bv[e]  (f16)
  gemm_h128<1><<<dim3(MM/128, DD/128, BB), 256, 0, stream>>>(
      wvH, 0, DD,  camH, (long)MM*DD, DD,
      Vt, (long)DD*MM, MM, bv);

  // scores = conf * (T @ cam^T + svec)  (f16 in/out, 2-phase pipelined)
  gemm_scores<<<dim3(MM/256, NN/128, BB), 512, 0, stream>>>(
      Th, camH, scores, lconf, svec);

  // row softmax, f16 in-place
  softmax_h<<<dim3(BB*NN), 256, 0, stream>>>(scores);

  // out = P @ Vt^T  (f16, 8-wave, 2-phase pipelined)
  gemm_pv<<<dim3(DD/256, NN/64, BB), 512, 0, stream>>>(
      scores, Vt, out);
}

// Round 15
// 196.056 us; speedup vs baseline: 1.3853x; 1.0154x over previous
//
#include <hip/hip_runtime.h>
#include <hip/hip_bf16.h>

#define BB 8
#define NN 2048
#define MM 2048
#define DD 512

typedef __attribute__((ext_vector_type(8))) _Float16 f16x8;
typedef __attribute__((ext_vector_type(4))) float f32x4;
typedef __attribute__((ext_vector_type(8))) unsigned short u16x8;

__device__ __forceinline__ unsigned short f2h(float x){
  union { _Float16 h; unsigned short u; } cv;
  cv.h = (_Float16)x;           // v_cvt_f16_f32, RTN-even
  return cv.u;
}
__device__ __forceinline__ float h2f(unsigned short u){
  union { unsigned short u; _Float16 h; } cv;
  cv.u = u;
  return (float)cv.h;
}
__device__ __forceinline__ f32x4 mfmah(f16x8 a, f16x8 b, f32x4 c){
  return __builtin_amdgcn_mfma_f32_16x16x32_f16(a, b, c, 0, 0, 0);
}

// async global->LDS, 16B per lane; LDS dest is wave-uniform base + lane*16
#define GLD16(gp, lp) __builtin_amdgcn_global_load_lds( \
    (const __attribute__((address_space(1))) void*)(gp), \
    (__attribute__((address_space(3))) void*)(lp), 16, 0, 0)

// wait until <= n vector-memory ops outstanding (lgkm/exp not waited)
#define WAITVM(n) __builtin_amdgcn_s_waitcnt(0xF70 | (n))

// batch->XCD swizzle: flat id f -> bz = f&7 (XCD presumed f%8), bijective
// (requires gridDim.z == 8)
__device__ __forceinline__ void swz_xyz(int& bn, int& bm, int& bz){
  int f = ((int)blockIdx.z * (int)gridDim.y + (int)blockIdx.y) * (int)gridDim.x
        + (int)blockIdx.x;
  bz = f & 7;
  int r = f >> 3;
  bn = r % (int)gridDim.x;
  bm = r / (int)gridDim.x;
}

// ---------------------------------------------------------------------------
// cvt16: f32 -> f16, float4-vectorized, grid-stride
// ---------------------------------------------------------------------------
__global__ __launch_bounds__(256) void cvt16_kernel(const float* __restrict__ in,
    unsigned short* __restrict__ out, int n4){
  int i = blockIdx.x*256 + threadIdx.x;
  const int stride = gridDim.x*256;
  for (; i < n4; i += stride){
    float4 v = ((const float4*)in)[i];
    ushort4 h; h.x=f2h(v.x); h.y=f2h(v.y); h.z=f2h(v.z); h.w=f2h(v.w);
    ((ushort4*)out)[i] = h;
  }
}

// ---------------------------------------------------------------------------
// cam_prep: one pass over camera f32 -> camH f16 AND svec[row] = cam.c2
// ---------------------------------------------------------------------------
__global__ __launch_bounds__(256) void cam_prep(const float* __restrict__ cam,
    const float* __restrict__ c2,
    unsigned short* __restrict__ camH,
    float* __restrict__ svec){
  const int t = threadIdx.x;
  const int l = t & 63;
  const size_t row = (size_t)blockIdx.x*4 + (t >> 6);
  const float4* r4 = (const float4*)(cam + row*DD);
  const float4* c4 = (const float4*)c2;
  float4 v0 = r4[l*2],   v1 = r4[l*2+1];
  float4 a0 = c4[l*2],   a1 = c4[l*2+1];
  float p = v0.x*a0.x + v0.y*a0.y + v0.z*a0.z + v0.w*a0.w
          + v1.x*a1.x + v1.y*a1.y + v1.z*a1.z + v1.w*a1.w;
  for (int o = 32; o; o >>= 1) p += __shfl_xor(p, o);
  if (l == 0) svec[row] = p;
  ushort4 h0; h0.x=f2h(v0.x); h0.y=f2h(v0.y); h0.z=f2h(v0.z); h0.w=f2h(v0.w);
  ushort4 h1; h1.x=f2h(v1.x); h1.y=f2h(v1.y); h1.z=f2h(v1.z); h1.w=f2h(v1.w);
  ushort4* dst = (ushort4*)(camH + row*DD);
  dst[l*2]   = h0;
  dst[l*2+1] = h1;
}

// ---------------------------------------------------------------------------
// K0: At[j][i] = sum_e Wq[e][i] * Wk[e][j], f32 accum, f16 out
// ---------------------------------------------------------------------------
__global__ __launch_bounds__(256) void at_kernel(const float* __restrict__ Wq,
                                                 const float* __restrict__ Wk,
                                                 unsigned short* __restrict__ atH){
  const int i0 = blockIdx.x * 32, j0 = blockIdx.y * 32;
  __shared__ float q_s[32][33];
  __shared__ float k_s[32][33];
  const int t = threadIdx.x;
  const int tx = t & 15, ty = t >> 4;
  float acc[2][2] = {{0.f,0.f},{0.f,0.f}};
  for (int e0 = 0; e0 < DD; e0 += 32){
    __syncthreads();
#pragma unroll
    for (int p = 0; p < 4; ++p){
      int idx = t + 256*p;
      int e = idx >> 5, c = idx & 31;
      q_s[e][c] = Wq[(size_t)(e0+e)*DD + i0 + c];
      k_s[e][c] = Wk[(size_t)(e0+e)*DD + j0 + c];
    }
    __syncthreads();
#pragma unroll 8
    for (int e = 0; e < 32; ++e){
      float q0 = q_s[e][2*tx], q1 = q_s[e][2*tx+1];
      float k0 = k_s[e][2*ty], k1 = k_s[e][2*ty+1];
      acc[0][0] += k0*q0; acc[0][1] += k0*q1;
      acc[1][0] += k1*q0; acc[1][1] += k1*q1;
    }
  }
#pragma unroll
  for (int a = 0; a < 2; ++a)
#pragma unroll
    for (int b = 0; b < 2; ++b)
      atH[(size_t)(j0 + 2*ty + a)*DD + i0 + 2*tx + b] = f2h(acc[a][b]);
}

// c2[d] = sum_e bq[e] * Wk[e][d]
__global__ __launch_bounds__(256) void c2_kernel(const float* __restrict__ bq,
                                                 const float* __restrict__ Wk,
                                                 float* __restrict__ c2){
  int d = blockIdx.x * 256 + threadIdx.x;
  float a = 0.f;
  for (int e = 0; e < DD; ++e) a += bq[e] * Wk[(size_t)e*DD + d];
  c2[d] = a;
}

// ---------------------------------------------------------------------------
// Plain f16 GEMM, BT form: O[row,col] = sum_k A[row,k]*B[col,k], f16 out.
// Block 128x128, 4 waves 2x2, wave 64x64 (4x4 frags of 16x16x32 f16).
// MODE 0: plain.  MODE 1: + bias[row].
// ---------------------------------------------------------------------------
template<int MODE>
__global__ __launch_bounds__(256) void gemm_h128(
    const unsigned short* __restrict__ Ag, long sA, int lda,
    const unsigned short* __restrict__ Bg, long sB, int ldb,
    unsigned short* __restrict__ O, long sO, int ldo,
    const float* __restrict__ bias)
{
  __shared__ __attribute__((aligned(16))) unsigned short Ah[128][40];
  __shared__ __attribute__((aligned(16))) unsigned short Bh[128][40];

  int bn, bm, bz; swz_xyz(bn, bm, bz);
  const int t = threadIdx.x;
  const int lane = t & 63, w = t >> 6;
  const int wrow = w >> 1, wcol = w & 1;
  const int lr = lane & 15, lk = (lane >> 4) << 3;

  f32x4 acc[4][4];
#pragma unroll
  for (int m = 0; m < 4; ++m)
#pragma unroll
    for (int n = 0; n < 4; ++n){ f32x4 z = {0.f,0.f,0.f,0.f}; acc[m][n] = z; }

  const unsigned short* Ap = Ag + (size_t)bz*(size_t)sA + ((size_t)bm*128)*(size_t)lda;
  const unsigned short* Bp = Bg + (size_t)bz*(size_t)sB + ((size_t)bn*128)*(size_t)ldb;

  const int sr = t >> 2;          // 0..63
  const int sc = (t & 3) * 8;

  for (int k0 = 0; k0 < DD; k0 += 32){
    __syncthreads();
#pragma unroll
    for (int p = 0; p < 2; ++p){
      int r = sr + 64*p;
      *(u16x8*)&Ah[r][sc] = *(const u16x8*)(Ap + (size_t)r*lda + k0 + sc);
      *(u16x8*)&Bh[r][sc] = *(const u16x8*)(Bp + (size_t)r*ldb + k0 + sc);
    }
    __syncthreads();

    f16x8 af[4], bf[4];
#pragma unroll
    for (int m = 0; m < 4; ++m) af[m] = *(const f16x8*)&Ah[wrow*64 + m*16 + lr][lk];
#pragma unroll
    for (int n = 0; n < 4; ++n) bf[n] = *(const f16x8*)&Bh[wcol*64 + n*16 + lr][lk];
#pragma unroll
    for (int m = 0; m < 4; ++m)
#pragma unroll
      for (int n = 0; n < 4; ++n)
        acc[m][n] = mfmah(af[m], bf[n], acc[m][n]);
  }

  const int orow = bm*128 + wrow*64;
  const int ocol = bn*128 + wcol*64;
#pragma unroll
  for (int m = 0; m < 4; ++m){
#pragma unroll
    for (int n = 0; n < 4; ++n){
      int col  = ocol + n*16 + lr;
      int row0 = orow + m*16 + ((lane >> 4) << 2);
#pragma unroll
      for (int r = 0; r < 4; ++r){
        int row = row0 + r;
        float v = acc[m][n][r];
        if constexpr (MODE == 1) v += bias[row];
        O[(size_t)bz*(size_t)sO + (size_t)row*ldo + col] = f2h(v);
      }
    }
  }
}

// ---------------------------------------------------------------------------
// scores f16 GEMM v3 (3-buffer, 2-tiles-ahead, counted vmcnt):
//   O[row,col] = f2h( conf[row]*(sum_k T[row,k]*cam[col,k] + svec[col]) )
// Block 128(rows) x 256(cols), 8 waves (2x4), wave 64x64 (4x4 frags),
// BK=32, 16 K-steps.  LDS 3 x 24KB = 72KB (2 blocks/CU).  Each STAGE = 3
// global_load_lds w16/wave.  RACE-SAFE per-iter order (R5 rule):
//   WAITVM(3) -> s_barrier -> STAGE((tt+2)%3) -> COMPUTE(tt%3)
// barrier certifies all waves finished COMPUTE(tt-1) (ran after previous
// barrier) before buffer (tt-1)%3 == (tt+2)%3 is overwritten; per-wave
// vmcnt(3) certifies its tile-tt loads (oldest 3 of <=6, FIFO) landed.
// DMA now gets ~2 MFMA phases to fly instead of <1 (T4: never drain to 0
// mid-loop).  XOR chunk swizzle pc = lc ^ (row&3) on both sides (T21).
// ---------------------------------------------------------------------------
__global__ __launch_bounds__(512) void gemm_scores(
    const unsigned short* __restrict__ Th, const unsigned short* __restrict__ camH,
    unsigned short* __restrict__ O,
    const float* __restrict__ conf, const float* __restrict__ svec)
{
  __shared__ unsigned short Ah[3][128][32];   // 24 KB
  __shared__ unsigned short Bh[3][256][32];   // 48 KB

  int bn, bm, bz; swz_xyz(bn, bm, bz);   // grid (8,16,8)
  const int t = threadIdx.x;             // 0..511
  const int lane = t & 63, w = t >> 6;   // 8 waves
  const int wrow = w >> 2, wcol = w & 3; // 2 x 4
  const int lr = lane & 15;
  const int c4 = lane >> 4;              // read chunk index 0..3

  const unsigned short* Ap = Th   + (size_t)bz*((size_t)NN*DD) + ((size_t)bm*128)*DD;
  const unsigned short* Bp = camH + (size_t)bz*((size_t)MM*DD) + ((size_t)bn*256)*DD;

  // staging: wave w stages A rows [16w,16w+16) (1 instr) and B rows
  // [32w,32w+32) (2 instrs of 16 rows).  lane i -> row base+(i>>2), phys
  // chunk (i&3); global source = logical chunk (i&3)^(row&3) (inverse swz;
  // XOR involution).  (row+16)&3 == row&3 -> same source col for B instr 2.
  const int sar  = w*16 + (lane >> 2);
  const int salc = (lane & 3) ^ (sar & 3);
  const unsigned short* gA = Ap + (size_t)sar*DD + salc*8;
  const int sbr  = w*32 + (lane >> 2);
  const int sblc = (lane & 3) ^ (sbr & 3);
  const unsigned short* gB = Bp + (size_t)sbr*DD + sblc*8;

#define SC_STAGE(bufi, kofs) do {                                  \
    GLD16(gA + (kofs),                 &Ah[bufi][w*16     ][0]);   \
    GLD16(gB + (kofs),                 &Bh[bufi][w*32     ][0]);   \
    GLD16(gB + (kofs) + (size_t)16*DD, &Bh[bufi][w*32 + 16][0]);   \
  } while(0)

#define SC_COMPUTE(bufi) do {                                      \
    f16x8 af[4], bf[4];                                            \
    _Pragma("unroll")                                              \
    for (int m = 0; m < 4; ++m){                                   \
      int row = wrow*64 + m*16 + lr;                               \
      int pc  = c4 ^ (row & 3);                                    \
      af[m] = *(const f16x8*)&Ah[bufi][row][pc*8];                 \
    }                                                              \
    _Pragma("unroll")                                              \
    for (int n = 0; n < 4; ++n){                                   \
      int row = wcol*64 + n*16 + lr;                               \
      int pc  = c4 ^ (row & 3);                                    \
      bf[n] = *(const f16x8*)&Bh[bufi][row][pc*8];                 \
    }                                                              \
    __builtin_amdgcn_s_setprio(1);                                 \
    _Pragma("unroll")                                              \
    for (int m = 0; m < 4; ++m)                                    \
      _Pragma("unroll")                                            \
      for (int n = 0; n < 4; ++n)                                  \
        acc[m][n] = mfmah(af[m], bf[n], acc[m][n]);                \
    __builtin_amdgcn_s_setprio(0);                                 \
  } while(0)

  f32x4 acc[4][4];
#pragma unroll
  for (int m = 0; m < 4; ++m)
#pragma unroll
    for (int n = 0; n < 4; ++n){ f32x4 z = {0.f,0.f,0.f,0.f}; acc[m][n] = z; }

  // prologue: stage tiles 0,1 (6 loads/wave in flight)
  SC_STAGE(0, 0);
  SC_STAGE(1, 32);

  // main loop: tiles 0..14, 2 ahead, counted vmcnt(3)
  for (int tt = 0; tt < 15; ++tt){
    WAITVM(3);                           // tile tt's 3 loads (oldest) landed
    __builtin_amdgcn_s_barrier();        // all waves: tile tt ready AND done
    __builtin_amdgcn_sched_barrier(0);   //   with COMPUTE(tt-1)
    if (tt < 14) SC_STAGE((tt+2)%3, (size_t)(tt+2)*32);
    SC_COMPUTE(tt%3);
  }
  // tail: tile 15 (buf 0), full drain
  WAITVM(0);
  __builtin_amdgcn_s_barrier();
  __builtin_amdgcn_sched_barrier(0);
  SC_COMPUTE(0);
#undef SC_STAGE
#undef SC_COMPUTE

  const int orow0 = bm*128 + wrow*64;
  const int ocol0 = bn*256 + wcol*64;
  const size_t obase = (size_t)bz*((size_t)NN*MM);
#pragma unroll
  for (int m = 0; m < 4; ++m){
#pragma unroll
    for (int n = 0; n < 4; ++n){
      int col  = ocol0 + n*16 + lr;
      float sv = svec[bz*MM + col];
      int row0 = orow0 + m*16 + ((lane >> 4) << 2);
#pragma unroll
      for (int r = 0; r < 4; ++r){
        int row = row0 + r;
        O[obase + (size_t)row*MM + col]
            = f2h(conf[bz*NN + row] * (acc[m][n][r] + sv));
      }
    }
  }
}

// ---------------------------------------------------------------------------
// Row softmax over M=2048, f16 in-place.  One 256-thread block per row,
// 8 elems/thread (u16x8).
// ---------------------------------------------------------------------------
__global__ __launch_bounds__(256) void softmax_h(unsigned short* __restrict__ scores){
  const size_t row = blockIdx.x;
  unsigned short* pr = scores + row * (size_t)MM;
  const int t = threadIdx.x;

  u16x8 v = ((const u16x8*)pr)[t];
  float x[8];
#pragma unroll
  for (int j = 0; j < 8; ++j) x[j] = h2f(v[j]);

  float mx = x[0];
#pragma unroll
  for (int j = 1; j < 8; ++j) mx = fmaxf(mx, x[j]);
  for (int o = 32; o; o >>= 1) mx = fmaxf(mx, __shfl_xor(mx, o));
  __shared__ float red[4];
  if ((t & 63) == 0) red[t >> 6] = mx;
  __syncthreads();
  mx = fmaxf(fmaxf(red[0], red[1]), fmaxf(red[2], red[3]));

  float e[8], s = 0.f;
#pragma unroll
  for (int j = 0; j < 8; ++j){ e[j] = __expf(x[j] - mx); s += e[j]; }
  for (int o = 32; o; o >>= 1) s += __shfl_xor(s, o);
  __syncthreads();               // everyone done reading red[] (max phase)
  if ((t & 63) == 0) red[t >> 6] = s;
  __syncthreads();
  float inv = 1.f / (red[0] + red[1] + red[2] + red[3]);

  u16x8 pv;
#pragma unroll
  for (int j = 0; j < 8; ++j) pv[j] = f2h(e[j] * inv);
  ((u16x8*)pr)[t] = pv;
}

// ---------------------------------------------------------------------------
// PV GEMM v2: out[n,e] = sum_m P[n,m]*Vt[e,m].  Block 64(n) x 256(e),
// 8 waves 1x8, wave 64n x 32e (4x2 frags), BK=64 (32 iters).  P f16 packed
// at lda=MM.  2-phase pipeline: double-buffered linear LDS staged via
// global_load_lds w16; issue next tile's DMA BEFORE computing current;
// ONE raw s_barrier + vmcnt(0) per iter (DMA flies under compute).
// XOR chunk swizzle pc = lc ^ (row&7) on BOTH pre-swizzled per-lane global
// source and fragment reads (T21).
// ---------------------------------------------------------------------------
__global__ __launch_bounds__(512) void gemm_pv(
    const unsigned short* __restrict__ P,
    const unsigned short* __restrict__ V,
    float* __restrict__ O)
{
  __shared__ unsigned short Ah[2][64][64];    // 16 KB
  __shared__ unsigned short Bh[2][256][64];   // 64 KB

  int bn, bm, bz; swz_xyz(bn, bm, bz);   // grid (2,32,8)
  const int t = threadIdx.x;             // 0..511
  const int lane = t & 63, w = t >> 6;   // 8 waves
  const int lr = lane & 15, lc0 = lane >> 4;

  const unsigned short* Ap = P + (size_t)bz*((size_t)NN*MM) + ((size_t)bm*64)*MM;
  const unsigned short* Bp = V + (size_t)bz*((size_t)DD*MM) + ((size_t)bn*256)*MM;

  // staging: wave w stages A rows 8w..8w+7 (1 instr) and B rows 32w..32w+31
  // (4 instrs).  lane i -> row base+(i>>3), phys chunk i&7; its global source
  // is logical chunk (i&7)^(row&7)  (inverse swizzle; XOR is an involution).
  const int arow = 8*w + (lane >> 3);
  const int alc  = (lane & 7) ^ (arow & 7);
  const unsigned short* gA = Ap + (size_t)arow*MM + alc*8;
  const int brow = 32*w + (lane >> 3);
  const int blc  = (lane & 7) ^ (brow & 7);   // same for all 4 B instrs (rows +8k)
  const unsigned short* gB = Bp + (size_t)brow*MM + blc*8;

#define PV_STAGE(bufi, kofs) do {                                   \
    GLD16(gA + (kofs),                 &Ah[bufi][8*w][0]);          \
    GLD16(gB + (kofs),                 &Bh[bufi][32*w     ][0]);    \
    GLD16(gB + (kofs) + (size_t)8*MM,  &Bh[bufi][32*w +  8][0]);    \
    GLD16(gB + (kofs) + (size_t)16*MM, &Bh[bufi][32*w + 16][0]);    \
    GLD16(gB + (kofs) + (size_t)24*MM, &Bh[bufi][32*w + 24][0]);    \
  } while(0)

  f32x4 acc[4][2];
#pragma unroll
  for (int m = 0; m < 4; ++m)
#pragma unroll
    for (int n = 0; n < 2; ++n){ f32x4 z = {0.f,0.f,0.f,0.f}; acc[m][n] = z; }

  // prologue: stage tile 0, wait, sync
  PV_STAGE(0, 0);
  WAITVM(0);
  __builtin_amdgcn_s_barrier();
  __builtin_amdgcn_sched_barrier(0);

  for (int tt = 0; tt < 32; ++tt){
    const int buf = tt & 1;
    if (tt < 31) PV_STAGE(buf^1, (size_t)(tt+1)*64);  // overwrites buffer
                                                      // computed at tt-1; all
                                                      // waves passed tt-1's
                                                      // end barrier -> safe
    f16x8 af[4][2], bf[2][2];
#pragma unroll
    for (int m = 0; m < 4; ++m){
      int row = m*16 + lr;
#pragma unroll
      for (int ks = 0; ks < 2; ++ks){
        int pc = (ks*4 + lc0) ^ (row & 7);
        af[m][ks] = *(const f16x8*)&Ah[buf][row][pc*8];
      }
    }
#pragma unroll
    for (int n = 0; n < 2; ++n){
      int row = w*32 + n*16 + lr;
#pragma unroll
      for (int ks = 0; ks < 2; ++ks){
        int pc = (ks*4 + lc0) ^ (row & 7);
        bf[n][ks] = *(const f16x8*)&Bh[buf][row][pc*8];
      }
    }
    __builtin_amdgcn_s_setprio(1);
#pragma unroll
    for (int m = 0; m < 4; ++m)
#pragma unroll
      for (int n = 0; n < 2; ++n){
        acc[m][n] = mfmah(af[m][0], bf[n][0], acc[m][n]);
        acc[m][n] = mfmah(af[m][1], bf[n][1], acc[m][n]);
      }
    __builtin_amdgcn_s_setprio(0);

    WAITVM(0);                          // this iter's DMA landed (flew under
    __builtin_amdgcn_s_barrier();       // the MFMA phase, not serialized)
    __builtin_amdgcn_sched_barrier(0);
  }
#undef PV_STAGE

  const int orow0 = bm*64;
  const int ocol0 = bn*256 + w*32;
#pragma unroll
  for (int m = 0; m < 4; ++m){
#pragma unroll
    for (int n = 0; n < 2; ++n){
      int col  = ocol0 + n*16 + lr;
      int row0 = orow0 + m*16 + ((lane >> 4) << 2);
#pragma unroll
      for (int r = 0; r < 4; ++r){
        int row = row0 + r;
        O[(size_t)bz*((size_t)NN*DD) + (size_t)row*DD + col] = acc[m][n][r];
      }
    }
  }
}

// ---------------------------------------------------------------------------
extern "C" void kernel_launch(void* const* d_in, const int* in_sizes, int n_in,
                              void* d_out, int out_size, void* d_ws, size_t ws_size,
                              hipStream_t stream) {
  const float* lidar  = (const float*)d_in[0];   // [B,N,D]
  const float* camera = (const float*)d_in[1];   // [B,M,D]
  const float* lconf  = (const float*)d_in[2];   // [B,N,1]
  // d_in[3] camera_confidence: unused by the reference
  const float* Wq = (const float*)d_in[4];
  const float* bq = (const float*)d_in[5];
  const float* Wk = (const float*)d_in[6];
  // d_in[7] bk: row-constant in scores -> softmax-invariant, dropped
  const float* Wv = (const float*)d_in[8];
  const float* bv = (const float*)d_in[9];
  float* out = (float*)d_out;                    // [B,N,D] f32

  // workspace layout (bytes)
  char* ws = (char*)d_ws;
  unsigned short* scores = (unsigned short*)(ws + 0);         // [B,N,M] f16 67.1MB (P in place)
  // transient aliases inside scores region (dead before scores is written):
  unsigned short* liH    = (unsigned short*)(ws + 0);         // [B,N,D] f16 16.8MB
  unsigned short* atH    = (unsigned short*)(ws + 16777216);  // [D,D]   f16 0.5MB
  unsigned short* wvH    = (unsigned short*)(ws + 17301504);  // [D,D]   f16 0.5MB
  float*          c2     = (float*)(ws + 17825792);           // [D]
  // persistent:
  unsigned short* Th     = (unsigned short*)(ws + 134217728); // [B,N,D] f16 16.8MB
  unsigned short* camH   = (unsigned short*)(ws + 150994944); // [B,M,D] f16 16.8MB
  unsigned short* Vt     = (unsigned short*)(ws + 167772160); // [B,D,M] f16 16.8MB
  float*          svec   = (float*)(ws + 184549376);          // [B,M]

  // prep: c2 first (cam_prep consumes it), then fused camera pass
  c2_kernel<<<dim3(2), 256, 0, stream>>>(bq, Wk, c2);
  cam_prep<<<dim3(BB*MM/4), 256, 0, stream>>>(camera, c2, camH, svec);
  cvt16_kernel<<<dim3(2048), 256, 0, stream>>>(lidar,  liH,  BB*NN*DD/4);
  cvt16_kernel<<<dim3(256),  256, 0, stream>>>(Wv,     wvH,  DD*DD/4);
  at_kernel<<<dim3(16,16), 256, 0, stream>>>(Wq, Wk, atH);

  // T = lidar @ At^T  (f16) -> Th
  gemm_h128<0><<<dim3(DD/128, NN/128, BB), 256, 0, stream>>>(
      liH, (long)NN*DD, DD,  atH, 0, DD,
      Th, (long)NN*DD, DD, nullptr);

  // Vt[e,m] = Wv[e,:].cam[m,:] + bv[e]  (f16)
  gemm_h128<1><<<dim3(MM/128, DD/128, BB), 256, 0, stream>>>(
      wvH, 0, DD,  camH, (long)MM*DD, DD,
      Vt, (long)DD*MM, MM, bv);

  // scores = conf * (T @ cam^T + svec)  (f16 in/out, 3-buffer pipelined)
  gemm_scores<<<dim3(MM/256, NN/128, BB), 512, 0, stream>>>(
      Th, camH, scores, lconf, svec);

  // row softmax, f16 in-place
  softmax_h<<<dim3(BB*NN), 256, 0, stream>>>(scores);

  // out = P @ Vt^T  (f16, 8-wave, 2-phase pipelined)
  gemm_pv<<<dim3(DD/256, NN/64, BB), 512, 0, stream>>>(
      scores, Vt, out);
}